// Round 17
// baseline (819.918 us; speedup 1.0000x reference)
//
#include <hip/hip_runtime.h>
#include <hip/hip_fp16.h>

#define LEAKY(v) ((v) < 0.0f ? 0.01f * (v) : (v))

typedef _Float16 half8 __attribute__((ext_vector_type(8)));
typedef float f32x4 __attribute__((ext_vector_type(4)));

__device__ __forceinline__ unsigned int pkrtz(float a, float b) {
  auto h = __builtin_amdgcn_cvt_pkrtz(a, b);  // __fp16 ext_vector(2)
  union { decltype(h) h2; unsigned int u; } c; c.h2 = h; return c.u;
}
__device__ __forceinline__ unsigned short f2h(float f) {
  union { _Float16 h; unsigned short u; } c; c.h = (_Float16)f; return c.u;
}
// monotone float<->uint order-preserving encode (for atomicMax/Min on floats; verified r4/r11)
__device__ __forceinline__ unsigned int fkey(float f) {
  unsigned int u = __float_as_uint(f);
  return ((int)u < 0) ? ~u : (u | 0x80000000u);
}
__device__ __forceinline__ float fdec(unsigned int k) {
  return __uint_as_float((k & 0x80000000u) ? (k ^ 0x80000000u) : ~k);
}

// ---------------- segment geometry ----------------

__global__ void seg_lb_kernel(const int* __restrict__ idx, int N, int S, int* __restrict__ seg_start) {
  int s = blockIdx.x * blockDim.x + threadIdx.x;
  if (s > S) return;
  int lo = 0, hi = N;
  while (lo < hi) {
    int mid = (lo + hi) >> 1;
    if (idx[mid] < s) lo = mid + 1; else hi = mid;
  }
  seg_start[s] = lo;
}

__global__ void seg_stat_kernel(const float* __restrict__ pos, const int* __restrict__ seg_start,
                                float* __restrict__ center, float* __restrict__ invr,
                                float* __restrict__ diam) {
  int s = blockIdx.x;
  int start = seg_start[s], end = seg_start[s + 1];
  int cnt = end - start;
  int lane = threadIdx.x; // 64 threads = 1 wave
  float sx = 0.f, sy = 0.f, sz = 0.f;
  for (int i = start + lane; i < end; i += 64) {
    sx += pos[3 * i + 0]; sy += pos[3 * i + 1]; sz += pos[3 * i + 2];
  }
  for (int o = 32; o > 0; o >>= 1) {
    sx += __shfl_down(sx, o); sy += __shfl_down(sy, o); sz += __shfl_down(sz, o);
  }
  float inv_cnt = 1.0f / fmaxf((float)cnt, 1.0f);
  float cx = __shfl(sx, 0) * inv_cnt;
  float cy = __shfl(sy, 0) * inv_cnt;
  float cz = __shfl(sz, 0) * inv_cnt;
  float m2 = 0.f;
  for (int i = start + lane; i < end; i += 64) {
    float dx = pos[3 * i + 0] - cx, dy = pos[3 * i + 1] - cy, dz = pos[3 * i + 2] - cz;
    m2 = fmaxf(m2, dx * dx + dy * dy + dz * dz);
  }
  for (int o = 32; o > 0; o >>= 1) m2 = fmaxf(m2, __shfl_down(m2, o));
  if (lane == 0) {
    float r = sqrtf(fmaxf(m2, 0.f));
    float rs = (r > 0.f) ? r : 1.0f;
    center[3 * s + 0] = cx; center[3 * s + 1] = cy; center[3 * s + 2] = cz;
    invr[s] = 1.0f / rs;
    diam[s] = (cnt > 0) ? 2.0f * rs : 0.0f;
  }
}

// ---- weight pre-convert: W[K][N] fp32 -> Wt[N][128] fp16 (k-chunks of 8, zero-padded) ----

__global__ void wconv_kernel(const float* __restrict__ W, int K, int N, unsigned short* __restrict__ Wt) {
  int i = blockIdx.x * 256 + threadIdx.x;
  if (i >= N * 16) return;
  int n = i >> 4, c = i & 15;
  union { uint4 u; unsigned short h[8]; } o;
#pragma unroll
  for (int e = 0; e < 8; ++e) {
    int k = c * 8 + e;
    float v = (k < K) ? W[(size_t)k * N + n] : 0.f;
    o.h[e] = f2h(v);
  }
  *(uint4*)&Wt[(size_t)n * 128 + c * 8] = o.u;
}

// ---------------- MFMA GEMM layer 1: persistent grid-stride (best-measured, r12/r13/r15) --------
// [x|pos_n] (K=67, padded) @ W1 -> y1 fp16 [N,128]. 128x128 tiles. STRIDED tile schedule
// (r16 lesson: chunked contiguous tiles serialize downstream atomics / hot lines; strided
// spreads them). B-fragments direct from global w1t (L2-resident). 2 barriers/tile.

__global__ __launch_bounds__(256, 2) void gemm1_kernel(
    const float* __restrict__ x, const float* __restrict__ pos, const int* __restrict__ idx,
    const float* __restrict__ center, const float* __restrict__ invr,
    const unsigned short* __restrict__ w1t, const float* __restrict__ b1,
    unsigned short* __restrict__ y1, float* __restrict__ gsum, float* __restrict__ gsq,
    int M, int ntiles) {
  __shared__ __align__(16) unsigned short Asm[128 * 128];
  __shared__ __align__(16) unsigned short Osm[128 * 128];
  const int tid = threadIdx.x;
  const int och = tid & 15;
  const int rr = tid >> 4;
  const int lane = tid & 63;
  const int wv = tid >> 6;
  const int wr = wv >> 1, wc = wv & 1;
  const int lr = lane & 15, lg = lane >> 4;
  const int tstep = gridDim.x;

  // persistent B fragments directly from global (K=96 -> 3 ks)
  half8 b[4][3];
#pragma unroll
  for (int cf = 0; cf < 4; ++cf) {
    int n = wc * 64 + cf * 16 + lr;
#pragma unroll
    for (int ks = 0; ks < 3; ++ks) {
      int c = ks * 4 + lg;
      b[cf][ks] = *(const half8*)&w1t[n * 128 + c * 8];
    }
  }
  float bb[4];
#pragma unroll
  for (int cf = 0; cf < 4; ++cf) bb[cf] = b1[wc * 64 + cf * 16 + lr];

  // zero A-chunks 9..11 once (staging writes only chunks 0..8; epilogue goes to Osm)
  if (tid < 128) {
    uint4 z = make_uint4(0u, 0u, 0u, 0u);
    int r = tid;
    *(uint4*)&Asm[r * 128 + ((9 ^ (r & 7)) << 3)] = z;
    *(uint4*)&Asm[r * 128 + ((10 ^ (r & 7)) << 3)] = z;
    *(uint4*)&Asm[r * 128 + ((11 ^ (r & 7)) << 3)] = z;
  }

  float4 pfx[8];
  float pp0 = 0.f, pp1 = 0.f, pp2 = 0.f, pc0 = 0.f, pc1 = 0.f, pc2 = 0.f, pir = 0.f;

  auto prefetch = [&](int tt) {
#pragma unroll
    for (int j = 0; j < 4; ++j) {
      int c = tid + 256 * j;
      int r = c >> 3, cc = c & 7;
      int row = tt * 128 + r;
      pfx[2 * j] = make_float4(0.f, 0.f, 0.f, 0.f);
      pfx[2 * j + 1] = make_float4(0.f, 0.f, 0.f, 0.f);
      if (row < M) {
        pfx[2 * j]     = *(const float4*)&x[(size_t)row * 64 + cc * 8];
        pfx[2 * j + 1] = *(const float4*)&x[(size_t)row * 64 + cc * 8 + 4];
      }
    }
    if (tid < 128) {
      int row = tt * 128 + tid;
      pp0 = pp1 = pp2 = pc0 = pc1 = pc2 = 0.f; pir = 0.f;
      if (row < M) {
        int s = idx[row];
        pp0 = pos[3 * row + 0]; pp1 = pos[3 * row + 1]; pp2 = pos[3 * row + 2];
        pc0 = center[3 * s + 0]; pc1 = center[3 * s + 1]; pc2 = center[3 * s + 2];
        pir = invr[s];
      }
    }
  };
  auto stageA = [&]() {
#pragma unroll
    for (int j = 0; j < 4; ++j) {
      int c = tid + 256 * j;
      int r = c >> 3, cc = c & 7;
      uint4 o;
      o.x = pkrtz(pfx[2 * j].x, pfx[2 * j].y);
      o.y = pkrtz(pfx[2 * j].z, pfx[2 * j].w);
      o.z = pkrtz(pfx[2 * j + 1].x, pfx[2 * j + 1].y);
      o.w = pkrtz(pfx[2 * j + 1].z, pfx[2 * j + 1].w);
      *(uint4*)&Asm[r * 128 + ((cc ^ (r & 7)) << 3)] = o;
    }
    if (tid < 128) {
      int r = tid;
      uint4 o = make_uint4(0u, 0u, 0u, 0u);
      o.x = pkrtz((pp0 - pc0) * pir, (pp1 - pc1) * pir);
      o.y = pkrtz((pp2 - pc2) * pir, 0.f);
      *(uint4*)&Asm[r * 128 + ((8 ^ (r & 7)) << 3)] = o;
    }
  };

  int t = blockIdx.x;
  prefetch(t);
  stageA();
  __syncthreads();

  float psum[8], psq[8];
#pragma unroll
  for (int c = 0; c < 8; ++c) { psum[c] = 0.f; psq[c] = 0.f; }

  const f32x4 fzero = {0.f, 0.f, 0.f, 0.f};

  for (;;) {
    const int tn = t + tstep;
    const bool more = tn < ntiles;
    if (more) prefetch(tn);  // issue early; latency hides under MFMA+epilogue
    f32x4 acc[4][4];
#pragma unroll
    for (int rf = 0; rf < 4; ++rf)
#pragma unroll
      for (int cf = 0; cf < 4; ++cf) acc[rf][cf] = fzero;
#pragma unroll
    for (int ks = 0; ks < 3; ++ks) {
      half8 a[4];
      int c = ks * 4 + lg;
#pragma unroll
      for (int rf = 0; rf < 4; ++rf) {
        int row = wr * 64 + rf * 16 + lr;
        a[rf] = *(const half8*)&Asm[row * 128 + ((c ^ (row & 7)) << 3)];
      }
#pragma unroll
      for (int cf = 0; cf < 4; ++cf)
#pragma unroll
        for (int rf = 0; rf < 4; ++rf)
          acc[rf][cf] = __builtin_amdgcn_mfma_f32_16x16x32_f16(a[rf], b[cf][ks], acc[rf][cf], 0, 0, 0);
    }
    // epilogue -> O region (Asm untouched; prev store of Osm done pre-barrier)
#pragma unroll
    for (int cf = 0; cf < 4; ++cf) {
      int col = wc * 64 + cf * 16 + lr;
#pragma unroll
      for (int rf = 0; rf < 4; ++rf) {
#pragma unroll
        for (int r = 0; r < 4; ++r) {
          int row = wr * 64 + rf * 16 + lg * 4 + r;
          Osm[row * 128 + (((col >> 3) ^ (row & 7)) << 3) + (col & 7)] = f2h(acc[rf][cf][r] + bb[cf]);
        }
      }
    }
    __syncthreads();  // O(t) complete; A(t) fully consumed
    // store O(t) + stats ; stage A(t+1) in the same phase
    const int row0 = t * 128;
#pragma unroll
    for (int j = 0; j < 8; ++j) {
      int r = rr + 16 * j;
      int row = row0 + r;
      if (row < M) {
        uint4 v = *(const uint4*)&Osm[r * 128 + ((och ^ (r & 7)) << 3)];
        *(uint4*)&y1[(size_t)row * 128 + och * 8] = v;
        union { uint4 u; _Float16 h[8]; } w; w.u = v;
#pragma unroll
        for (int c = 0; c < 8; ++c) { float f = (float)w.h[c]; psum[c] += f; psq[c] += f * f; }
      }
    }
    if (!more) break;
    stageA();
    t = tn;
    __syncthreads();  // A(t+1) ready; O free for next epilogue
  }

  __syncthreads();
  float* redS = (float*)Osm;
  float* redQ = redS + 16 * 128;
#pragma unroll
  for (int c = 0; c < 8; ++c) {
    redS[rr * 128 + och * 8 + c] = psum[c];
    redQ[rr * 128 + och * 8 + c] = psq[c];
  }
  __syncthreads();
  if (tid < 128) {
    float s = 0.f, q = 0.f;
#pragma unroll
    for (int g = 0; g < 16; ++g) { s += redS[g * 128 + tid]; q += redQ[g * 128 + tid]; }
    atomicAdd(&gsum[tid], s);
    atomicAdd(&gsq[tid], q);
  }
}

// ---------------- MFMA GEMM layer 2 + in-register fused segment pool (r15 schedule + fast path) -
// leaky(a1*y1+c1) [1M,128] @ W2; pool max/min and column stats computed DIRECTLY from the
// f32 accumulators. Row-permuted A-staging makes each lane's 16 fragment rows CONTIGUOUS in
// point order. Double-buffered A -> 1 barrier/tile. STRIDED tile schedule (r16 lesson:
// chunked serializes atomics on hot lines; strided spreads them). Uniform-window fast path:
// ~84% of 16-row windows lie in one segment -> skip run bookkeeping, same atomic pattern.

__global__ __launch_bounds__(256, 2) void gemm2_kernel(
    const unsigned short* __restrict__ y1,
    const unsigned short* __restrict__ a1h, const unsigned short* __restrict__ c1h,
    const unsigned short* __restrict__ w2t, const float* __restrict__ b2,
    const int* __restrict__ idx,
    unsigned int* __restrict__ segmx, unsigned int* __restrict__ segmn,
    float* __restrict__ gsum, float* __restrict__ gsq,
    int M, int ntiles) {
  __shared__ __align__(16) unsigned short Abuf[2][128 * 128];
  __shared__ int sbuf[2][128];
  const int tid = threadIdx.x;
  const int col0 = blockIdx.x * 128;
  const int och = tid & 15;
  const int rr = tid >> 4;  // 0..15
  const int tstep = gridDim.y;

  // activation params for this thread's fixed k-chunk
  const _Float16* ap = (const _Float16*)a1h;
  const _Float16* cp = (const _Float16*)c1h;
  _Float16 av[8], cv[8];
#pragma unroll
  for (int q = 0; q < 8; ++q) { av[q] = ap[och * 8 + q]; cv[q] = cp[och * 8 + q]; }

  int t = blockIdx.y;
  // issue A(t0) loads + sids(t0) first (latency hides under B setup)
  uint4 pf[8];
  // row permutation: tile row p holds original row perm(p); perm swaps bits[5:4]<->[3:2]
  auto perm = [](int p) { return (p & 0x43) | ((p & 0x30) >> 2) | ((p & 0x0c) << 2); };
#pragma unroll
  for (int j = 0; j < 8; ++j) {
    int r = rr + 16 * j;
    int row = t * 128 + perm(r);
    pf[j] = make_uint4(0u, 0u, 0u, 0u);
    if (row < M) pf[j] = *(const uint4*)&y1[(size_t)row * 128 + och * 8];
  }
  if (tid < 128) {
    int row = t * 128 + tid;
    sbuf[0][tid] = (row < M) ? idx[row] : -1;
  }

  // stage B tile through Abuf[0] (once)
#pragma unroll
  for (int j = 0; j < 8; ++j) {
    int n = rr + 16 * j;
    uint4 v = *(const uint4*)&w2t[(size_t)(col0 + n) * 128 + och * 8];
    *(uint4*)&Abuf[0][n * 128 + ((och ^ (n & 7)) << 3)] = v;
  }
  __syncthreads();

  const int lane = tid & 63;
  const int wv = tid >> 6;
  const int wr = wv >> 1, wc = wv & 1;
  const int lr = lane & 15, lg = lane >> 4;

  // persistent B fragments (16 half8 = 64 VGPR)
  half8 b[4][4];
#pragma unroll
  for (int cf = 0; cf < 4; ++cf) {
    int n = wc * 64 + cf * 16 + lr;
#pragma unroll
    for (int ks = 0; ks < 4; ++ks) {
      int c = ks * 4 + lg;
      b[cf][ks] = *(const half8*)&Abuf[0][n * 128 + ((c ^ (n & 7)) << 3)];
    }
  }
  float bb[4];
#pragma unroll
  for (int cf = 0; cf < 4; ++cf) bb[cf] = b2[col0 + wc * 64 + cf * 16 + lr];
  __syncthreads();  // B-frag extraction done; Abuf[0] free

  // stage A(t0) (fused act) into Abuf[0]
#pragma unroll
  for (int j = 0; j < 8; ++j) {
    int r = rr + 16 * j;
    union { uint4 u; _Float16 h[8]; } w; w.u = pf[j];
#pragma unroll
    for (int q = 0; q < 8; ++q) {
      _Float16 v = w.h[q] * av[q] + cv[q];
      w.h[q] = (v < (_Float16)0.f) ? v * (_Float16)0.01f : v;
    }
    *(uint4*)&Abuf[0][r * 128 + ((och ^ (r & 7)) << 3)] = w.u;
  }
  __syncthreads();  // A(t0) ready

  float csum[4], csq[4];
#pragma unroll
  for (int cf = 0; cf < 4; ++cf) { csum[cf] = 0.f; csq[cf] = 0.f; }

  const f32x4 fzero = {0.f, 0.f, 0.f, 0.f};
  int p = 0;

  for (;;) {
    const int tn = t + tstep;
    const bool more = tn < ntiles;
    // issue next tile's loads + sids early (into the spare buffers)
    if (more) {
#pragma unroll
      for (int j = 0; j < 8; ++j) {
        int r = rr + 16 * j;
        int row = tn * 128 + perm(r);
        pf[j] = make_uint4(0u, 0u, 0u, 0u);
        if (row < M) pf[j] = *(const uint4*)&y1[(size_t)row * 128 + och * 8];
      }
      if (tid < 128) {
        int row = tn * 128 + tid;
        sbuf[p ^ 1][tid] = (row < M) ? idx[row] : -1;
      }
    }
    // MFMA on Abuf[p] (= permuted A(t))
    f32x4 acc[4][4];
#pragma unroll
    for (int rf = 0; rf < 4; ++rf)
#pragma unroll
      for (int cf = 0; cf < 4; ++cf) acc[rf][cf] = fzero;
    const unsigned short* Ac = Abuf[p];
#pragma unroll
    for (int ks = 0; ks < 4; ++ks) {
      half8 a[4];
      int c = ks * 4 + lg;
#pragma unroll
      for (int rf = 0; rf < 4; ++rf) {
        int row = wr * 64 + rf * 16 + lr;
        a[rf] = *(const half8*)&Ac[row * 128 + ((c ^ (row & 7)) << 3)];
      }
#pragma unroll
      for (int cf = 0; cf < 4; ++cf)
#pragma unroll
        for (int rf = 0; rf < 4; ++rf)
          acc[rf][cf] = __builtin_amdgcn_mfma_f32_16x16x32_f16(a[rf], b[cf][ks], acc[rf][cf], 0, 0, 0);
    }
    // in-register scan: lane's fragment rows are original rows wr*64+lg*16+k (k=0..15)
    {
      const int* sp = &sbuf[p][wr * 64 + lg * 16];
      int4 s0 = *(const int4*)&sp[0];
      int4 s1 = *(const int4*)&sp[4];
      int4 s2 = *(const int4*)&sp[8];
      int4 s3 = *(const int4*)&sp[12];
      int sid[16] = { s0.x, s0.y, s0.z, s0.w, s1.x, s1.y, s1.z, s1.w,
                      s2.x, s2.y, s2.z, s2.w, s3.x, s3.y, s3.z, s3.w };
      bool uni = true;
#pragma unroll
      for (int k = 1; k < 16; ++k) uni = uni && (sid[k] == sid[0]);
      if (uni) {
        if (sid[0] >= 0) {
          // fast path: whole window in one segment, all rows valid (same atomics as run-scan)
#pragma unroll
          for (int cf = 0; cf < 4; ++cf) {
            const unsigned col = col0 + wc * 64 + cf * 16 + lr;
            float mx = -3.4e38f, mn = 3.4e38f;
#pragma unroll
            for (int rf = 0; rf < 4; ++rf)
#pragma unroll
              for (int r = 0; r < 4; ++r) {
                float v = acc[rf][cf][r] + bb[cf];
                mx = fmaxf(mx, v); mn = fminf(mn, v);
                csum[cf] += v; csq[cf] += v * v;
              }
            atomicMax(&segmx[(size_t)sid[0] * 256 + col], fkey(mx));
            atomicMin(&segmn[(size_t)sid[0] * 256 + col], fkey(mn));
          }
        }
      } else {
#pragma unroll
        for (int cf = 0; cf < 4; ++cf) {
          const unsigned col = col0 + wc * 64 + cf * 16 + lr;
          float vv[16];
#pragma unroll
          for (int rf = 0; rf < 4; ++rf)
#pragma unroll
            for (int r = 0; r < 4; ++r) vv[rf * 4 + r] = acc[rf][cf][r] + bb[cf];
          // column stats (invalid rows have sid==-1 -> masked)
#pragma unroll
          for (int k = 0; k < 16; ++k) {
            float vk = (sid[k] >= 0) ? vv[k] : 0.f;
            csum[cf] += vk; csq[cf] += vk * vk;
          }
          // run scan + atomic flush
          int cur = sid[0];
          float mx = vv[0], mn = vv[0];
#pragma unroll
          for (int k = 1; k < 16; ++k) {
            if (sid[k] != cur) {
              if (cur >= 0) {
                atomicMax(&segmx[(size_t)cur * 256 + col], fkey(mx));
                atomicMin(&segmn[(size_t)cur * 256 + col], fkey(mn));
              }
              cur = sid[k]; mx = vv[k]; mn = vv[k];
            } else {
              mx = fmaxf(mx, vv[k]); mn = fminf(mn, vv[k]);
            }
          }
          if (cur >= 0) {
            atomicMax(&segmx[(size_t)cur * 256 + col], fkey(mx));
            atomicMin(&segmn[(size_t)cur * 256 + col], fkey(mn));
          }
        }
      }
    }
    if (!more) break;
    // stage A(t+1) into the spare buffer (everyone finished MFMA on it pre-prev-barrier)
#pragma unroll
    for (int j = 0; j < 8; ++j) {
      int r = rr + 16 * j;
      union { uint4 u; _Float16 h[8]; } w; w.u = pf[j];
#pragma unroll
      for (int q = 0; q < 8; ++q) {
        _Float16 v = w.h[q] * av[q] + cv[q];
        w.h[q] = (v < (_Float16)0.f) ? v * (_Float16)0.01f : v;
      }
      *(uint4*)&Abuf[p ^ 1][r * 128 + ((och ^ (r & 7)) << 3)] = w.u;
    }
    t = tn; p ^= 1;
    __syncthreads();  // A(t) ready; old buffer & sbuf slot free for next prefetch
  }

  // stats: reduce across lg lanes (same column), then atomics from lg==0 lanes
#pragma unroll
  for (int cf = 0; cf < 4; ++cf) {
    csum[cf] += __shfl_xor(csum[cf], 16);
    csum[cf] += __shfl_xor(csum[cf], 32);
    csq[cf] += __shfl_xor(csq[cf], 16);
    csq[cf] += __shfl_xor(csq[cf], 32);
  }
  if (lg == 0) {
#pragma unroll
    for (int cf = 0; cf < 4; ++cf) {
      int col = col0 + wc * 64 + cf * 16 + lr;
      atomicAdd(&gsum[col], csum[cf]);
      atomicAdd(&gsq[col], csq[cf]);
    }
  }
}

// ---------------- shared fp32 GEMM micro-kernel (global MLP only; latency-dominated,
// measured faster than the 128-tile MFMA port at M=10000 -- r9 post-mortem) ----------------

__device__ __forceinline__ void mm_tile(const float* __restrict__ As, const float* __restrict__ Bs,
                                        int bk, int tr, int tc, float acc[4][8]) {
  for (int k4 = 0; k4 < bk; k4 += 4) {
    float4 a[4];
#pragma unroll
    for (int r = 0; r < 4; ++r) a[r] = *(const float4*)&As[(tr * 4 + r) * 68 + k4];
#pragma unroll
    for (int kk = 0; kk < 4; ++kk) {
      float4 w0 = *(const float4*)&Bs[(k4 + kk) * 128 + tc * 8];
      float4 w1 = *(const float4*)&Bs[(k4 + kk) * 128 + tc * 8 + 4];
#pragma unroll
      for (int r = 0; r < 4; ++r) {
        float av = (kk == 0) ? a[r].x : (kk == 1) ? a[r].y : (kk == 2) ? a[r].z : a[r].w;
        acc[r][0] = fmaf(av, w0.x, acc[r][0]);
        acc[r][1] = fmaf(av, w0.y, acc[r][1]);
        acc[r][2] = fmaf(av, w0.z, acc[r][2]);
        acc[r][3] = fmaf(av, w0.w, acc[r][3]);
        acc[r][4] = fmaf(av, w1.x, acc[r][4]);
        acc[r][5] = fmaf(av, w1.y, acc[r][5]);
        acc[r][6] = fmaf(av, w1.z, acc[r][6]);
        acc[r][7] = fmaf(av, w1.w, acc[r][7]);
      }
    }
  }
}

__device__ __forceinline__ void stats_reduce(float* redS, float* redQ,
                                             const float psum[8], const float psq[8],
                                             int tr, int tc, int tid,
                                             float* __restrict__ gsum, float* __restrict__ gsq, int col0) {
  __syncthreads();
#pragma unroll
  for (int c = 0; c < 8; ++c) {
    redS[tr * 128 + tc * 8 + c] = psum[c];
    redQ[tr * 128 + tc * 8 + c] = psq[c];
  }
  __syncthreads();
  if (tid < 128) {
    float s = 0.f, q = 0.f;
#pragma unroll
    for (int r = 0; r < 16; ++r) { s += redS[r * 128 + tid]; q += redQ[r * 128 + tid]; }
    atomicAdd(&gsum[col0 + tid], s);
    atomicAdd(&gsq[col0 + tid], q);
  }
}

// ---------------- global MLP GEMMs (M=10000) ----------------

template <bool NORM>
__global__ __launch_bounds__(256) void gemmG_kernel(
    const float* __restrict__ A, int lda, int K, int M,
    const float* __restrict__ an, const float* __restrict__ cn,
    const float* __restrict__ W, const float* __restrict__ bias,
    float* __restrict__ Y, float* __restrict__ gsum, float* __restrict__ gsq) {
  __shared__ float As[64 * 68];
  __shared__ float Bs[64 * 128];
  const int tid = threadIdx.x;
  const int row0 = blockIdx.x * 64;
  const int col0 = blockIdx.y * 128;
  const int tr = tid >> 4, tc = tid & 15;
  float acc[4][8];
#pragma unroll
  for (int r = 0; r < 4; ++r)
#pragma unroll
    for (int c = 0; c < 8; ++c) acc[r][c] = 0.f;

  const int nkb = (K + 63) >> 6;
  for (int kb = 0; kb < nkb; ++kb) {
    if (kb) __syncthreads();
    for (int e = tid; e < 64 * 64; e += 256) {
      int r = e >> 6, c = e & 63;
      int row = row0 + r, k = kb * 64 + c;
      float v = 0.f;
      if (row < M && k < K) {
        v = A[(size_t)row * lda + k];
        if (NORM) { v = an[k] * v + cn[k]; v = LEAKY(v); }
      }
      As[r * 68 + c] = v;
    }
    for (int e = tid; e < 64 * 32; e += 256) {
      int r = e >> 5, c4 = e & 31;
      int k = kb * 64 + r;
      float4 v = make_float4(0.f, 0.f, 0.f, 0.f);
      if (k < K) v = *(const float4*)&W[(size_t)k * 512 + col0 + c4 * 4];
      *(float4*)&Bs[r * 128 + c4 * 4] = v;
    }
    __syncthreads();
    mm_tile(As, Bs, 64, tr, tc, acc);
  }

  float psum[8], psq[8];
#pragma unroll
  for (int c = 0; c < 8; ++c) { psum[c] = 0.f; psq[c] = 0.f; }
#pragma unroll
  for (int r = 0; r < 4; ++r) {
    int row = row0 + tr * 4 + r;
    if (row < M) {
      float yv[8];
#pragma unroll
      for (int c = 0; c < 8; ++c) {
        yv[c] = acc[r][c] + bias[col0 + tc * 8 + c];
        psum[c] += yv[c]; psq[c] += yv[c] * yv[c];
      }
      *(float4*)&Y[(size_t)row * 512 + col0 + tc * 8] = make_float4(yv[0], yv[1], yv[2], yv[3]);
      *(float4*)&Y[(size_t)row * 512 + col0 + tc * 8 + 4] = make_float4(yv[4], yv[5], yv[6], yv[7]);
    }
  }
  stats_reduce(As, Bs, psum, psq, tr, tc, tid, gsum, gsq, col0);
}

// ---------------- finalize batch-norm affine ----------------

__global__ void finalize_kernel(const float* __restrict__ gsum, const float* __restrict__ gsq,
                                const float* __restrict__ g, const float* __restrict__ be,
                                float invn, int C, float* __restrict__ a, float* __restrict__ c,
                                unsigned short* __restrict__ ah, unsigned short* __restrict__ chh) {
  int j = blockIdx.x * blockDim.x + threadIdx.x;
  if (j >= C) return;
  float mu = gsum[j] * invn;
  float var = gsq[j] * invn - mu * mu;
  float aj = g[j] * rsqrtf(var + 1e-5f);
  float cj = be[j] - mu * aj;
  a[j] = aj;
  c[j] = cj;
  if (ah) { ah[j] = f2h(aj); chh[j] = f2h(cj); }
}

// ---------------- pool finalize: decode seg max/min, apply norm+leaky (verified r4/r11) --------
// pool val = leaky(a2*(a2>=0 ? segmax : segmin) + c2)  (affine+leaky monotone/antitone trick)

__global__ void poolfin_kernel(const unsigned int* __restrict__ segmx, const unsigned int* __restrict__ segmn,
                               const int* __restrict__ seg_start,
                               const float* __restrict__ a2, const float* __restrict__ c2,
                               const float* __restrict__ diam, float* __restrict__ hg) {
  int s = blockIdx.x;
  int j = threadIdx.x;  // 256
  bool nonempty = seg_start[s + 1] > seg_start[s];
  float aj = a2[j], cj = c2[j];
  unsigned int k = (aj >= 0.f) ? segmx[(size_t)s * 256 + j] : segmn[(size_t)s * 256 + j];
  float f = fdec(k);
  float v = aj * f + cj;
  v = LEAKY(v);
  hg[(size_t)s * 257 + j] = nonempty ? v : 0.0f;
  if (j == 0) hg[(size_t)s * 257 + 256] = diam[s];
}

// ---------------- final elementwise norm+leaky -> out ----------------

__global__ void final_kernel(const float* __restrict__ y4, const float* __restrict__ a4,
                             const float* __restrict__ c4, float* __restrict__ out, int total) {
  int i = blockIdx.x * blockDim.x + threadIdx.x;
  if (i >= total) return;
  int j = i & 511;
  float v = a4[j] * y4[i] + c4[j];
  out[i] = LEAKY(v);
}

// ---------------- launch ----------------

extern "C" void kernel_launch(void* const* d_in, const int* in_sizes, int n_in,
                              void* d_out, int out_size, void* d_ws, size_t ws_size,
                              hipStream_t stream) {
  const float* pos  = (const float*)d_in[0];
  const float* x    = (const float*)d_in[1];
  const int*   idx  = (const int*)d_in[2];
  const float* W1   = (const float*)d_in[4];
  const float* b1   = (const float*)d_in[5];
  const float* g1   = (const float*)d_in[6];
  const float* be1  = (const float*)d_in[7];
  const float* W2   = (const float*)d_in[8];
  const float* b2   = (const float*)d_in[9];
  const float* g2   = (const float*)d_in[10];
  const float* be2  = (const float*)d_in[11];
  const float* GW1  = (const float*)d_in[12];
  const float* Gb1  = (const float*)d_in[13];
  const float* Gg1  = (const float*)d_in[14];
  const float* Gbe1 = (const float*)d_in[15];
  const float* GW2  = (const float*)d_in[16];
  const float* Gb2  = (const float*)d_in[17];
  const float* Gg2  = (const float*)d_in[18];
  const float* Gbe2 = (const float*)d_in[19];
  float* out = (float*)d_out;

  const int N = in_sizes[0] / 3;  // 1,000,000
  const int S = 10000;            // num_segments (fixed by problem setup)

  char* ws = (char*)d_ws;
  size_t off = 0;
  auto take = [&](size_t bytes) -> char* {
    char* p = ws + off;
    off = (off + bytes + 255) & ~(size_t)255;
    return p;
  };
  int*   seg_start = (int*)take((size_t)(S + 1) * sizeof(int));
  float* center    = (float*)take((size_t)S * 3 * sizeof(float));
  float* invr      = (float*)take((size_t)S * sizeof(float));
  float* diam      = (float*)take((size_t)S * sizeof(float));
  float* stats     = (float*)take(2816 * sizeof(float));
  float* gsum1 = stats,        *gsq1 = stats + 128;
  float* gsum2 = stats + 256,  *gsq2 = stats + 512;
  float* gsum3 = stats + 768,  *gsq3 = stats + 1280;
  float* gsum4 = stats + 1792, *gsq4 = stats + 2304;
  float* par = (float*)take(2816 * sizeof(float));
  float* a1 = par,        *c1 = par + 256;
  float* a2 = par + 512,  *c2 = par + 768;
  float* a3 = par + 1024, *c3 = par + 1536;
  float* a4 = par + 2048, *c4 = par + 2560;
  unsigned short* a1h = (unsigned short*)take(128 * 2);
  unsigned short* c1h = (unsigned short*)take(128 * 2);
  unsigned short* w1t = (unsigned short*)take((size_t)128 * 128 * 2);
  unsigned short* w2t = (unsigned short*)take((size_t)256 * 128 * 2);
  float* hg = (float*)take((size_t)S * 257 * sizeof(float));
  float* y3 = (float*)take((size_t)S * 512 * sizeof(float));
  float* y4 = (float*)take((size_t)S * 512 * sizeof(float));
  unsigned int* segmx = (unsigned int*)take((size_t)S * 256 * sizeof(unsigned int));
  unsigned int* segmn = (unsigned int*)take((size_t)S * 256 * sizeof(unsigned int));
  unsigned short* y1 = (unsigned short*)take((size_t)N * 128 * 2);
  (void)ws_size; (void)n_in; (void)out_size;

  hipMemsetAsync(stats, 0, 2816 * sizeof(float), stream);
  hipMemsetAsync(segmx, 0x00, (size_t)S * 256 * sizeof(unsigned int), stream);
  hipMemsetAsync(segmn, 0xFF, (size_t)S * 256 * sizeof(unsigned int), stream);

  wconv_kernel<<<(128 * 16 + 255) / 256, 256, 0, stream>>>(W1, 67, 128, w1t);
  wconv_kernel<<<(256 * 16 + 255) / 256, 256, 0, stream>>>(W2, 128, 256, w2t);

  seg_lb_kernel<<<(S + 1 + 255) / 256, 256, 0, stream>>>(idx, N, S, seg_start);
  seg_stat_kernel<<<S, 64, 0, stream>>>(pos, seg_start, center, invr, diam);

  const int ntiles = (N + 127) / 128;
  gemm1_kernel<<<512, 256, 0, stream>>>(x, pos, idx, center, invr, w1t, b1, y1, gsum1, gsq1, N, ntiles);
  finalize_kernel<<<1, 128, 0, stream>>>(gsum1, gsq1, g1, be1, 1.0f / (float)N, 128, a1, c1, a1h, c1h);

  gemm2_kernel<<<dim3(2, 256), 256, 0, stream>>>(y1, a1h, c1h, w2t, b2, idx, segmx, segmn,
                                                 gsum2, gsq2, N, ntiles);
  finalize_kernel<<<1, 256, 0, stream>>>(gsum2, gsq2, g2, be2, 1.0f / (float)N, 256, a2, c2, nullptr, nullptr);

  poolfin_kernel<<<S, 256, 0, stream>>>(segmx, segmn, seg_start, a2, c2, diam, hg);

  gemmG_kernel<false><<<dim3((S + 63) / 64, 4), 256, 0, stream>>>(hg, 257, 257, S, nullptr, nullptr,
                                                                  GW1, Gb1, y3, gsum3, gsq3);
  finalize_kernel<<<2, 256, 0, stream>>>(gsum3, gsq3, Gg1, Gbe1, 1.0f / (float)S, 512, a3, c3, nullptr, nullptr);

  gemmG_kernel<true><<<dim3((S + 63) / 64, 4), 256, 0, stream>>>(y3, 512, 512, S, a3, c3,
                                                                 GW2, Gb2, y4, gsum4, gsq4);
  finalize_kernel<<<2, 256, 0, stream>>>(gsum4, gsq4, Gg2, Gbe2, 1.0f / (float)S, 512, a4, c4, nullptr, nullptr);

  final_kernel<<<(S * 512 + 255) / 256, 256, 0, stream>>>(y4, a4, c4, out, S * 512);
}

// Round 18
// 690.090 us; speedup vs baseline: 1.1881x; 1.1881x over previous
//
#include <hip/hip_runtime.h>
#include <hip/hip_fp16.h>

#define LEAKY(v) ((v) < 0.0f ? 0.01f * (v) : (v))

typedef _Float16 half8 __attribute__((ext_vector_type(8)));
typedef float f32x4 __attribute__((ext_vector_type(4)));

__device__ __forceinline__ unsigned int pkrtz(float a, float b) {
  auto h = __builtin_amdgcn_cvt_pkrtz(a, b);  // __fp16 ext_vector(2)
  union { decltype(h) h2; unsigned int u; } c; c.h2 = h; return c.u;
}
__device__ __forceinline__ unsigned short f2h(float f) {
  union { _Float16 h; unsigned short u; } c; c.h = (_Float16)f; return c.u;
}
// monotone float<->uint order-preserving encode (for atomicMax/Min on floats; verified r4/r11)
__device__ __forceinline__ unsigned int fkey(float f) {
  unsigned int u = __float_as_uint(f);
  return ((int)u < 0) ? ~u : (u | 0x80000000u);
}
__device__ __forceinline__ float fdec(unsigned int k) {
  return __uint_as_float((k & 0x80000000u) ? (k ^ 0x80000000u) : ~k);
}

// ---------------- segment geometry ----------------

__global__ void seg_lb_kernel(const int* __restrict__ idx, int N, int S, int* __restrict__ seg_start) {
  int s = blockIdx.x * blockDim.x + threadIdx.x;
  if (s > S) return;
  int lo = 0, hi = N;
  while (lo < hi) {
    int mid = (lo + hi) >> 1;
    if (idx[mid] < s) lo = mid + 1; else hi = mid;
  }
  seg_start[s] = lo;
}

__global__ void seg_stat_kernel(const float* __restrict__ pos, const int* __restrict__ seg_start,
                                float* __restrict__ center, float* __restrict__ invr,
                                float* __restrict__ diam) {
  int s = blockIdx.x;
  int start = seg_start[s], end = seg_start[s + 1];
  int cnt = end - start;
  int lane = threadIdx.x; // 64 threads = 1 wave
  float sx = 0.f, sy = 0.f, sz = 0.f;
  for (int i = start + lane; i < end; i += 64) {
    sx += pos[3 * i + 0]; sy += pos[3 * i + 1]; sz += pos[3 * i + 2];
  }
  for (int o = 32; o > 0; o >>= 1) {
    sx += __shfl_down(sx, o); sy += __shfl_down(sy, o); sz += __shfl_down(sz, o);
  }
  float inv_cnt = 1.0f / fmaxf((float)cnt, 1.0f);
  float cx = __shfl(sx, 0) * inv_cnt;
  float cy = __shfl(sy, 0) * inv_cnt;
  float cz = __shfl(sz, 0) * inv_cnt;
  float m2 = 0.f;
  for (int i = start + lane; i < end; i += 64) {
    float dx = pos[3 * i + 0] - cx, dy = pos[3 * i + 1] - cy, dz = pos[3 * i + 2] - cz;
    m2 = fmaxf(m2, dx * dx + dy * dy + dz * dz);
  }
  for (int o = 32; o > 0; o >>= 1) m2 = fmaxf(m2, __shfl_down(m2, o));
  if (lane == 0) {
    float r = sqrtf(fmaxf(m2, 0.f));
    float rs = (r > 0.f) ? r : 1.0f;
    center[3 * s + 0] = cx; center[3 * s + 1] = cy; center[3 * s + 2] = cz;
    invr[s] = 1.0f / rs;
    diam[s] = (cnt > 0) ? 2.0f * rs : 0.0f;
  }
}

// ---- weight pre-convert: W[K][N] fp32 -> Wt[N][128] fp16 (k-chunks of 8, zero-padded) ----

__global__ void wconv_kernel(const float* __restrict__ W, int K, int N, unsigned short* __restrict__ Wt) {
  int i = blockIdx.x * 256 + threadIdx.x;
  if (i >= N * 16) return;
  int n = i >> 4, c = i & 15;
  union { uint4 u; unsigned short h[8]; } o;
#pragma unroll
  for (int e = 0; e < 8; ++e) {
    int k = c * 8 + e;
    float v = (k < K) ? W[(size_t)k * N + n] : 0.f;
    o.h[e] = f2h(v);
  }
  *(uint4*)&Wt[(size_t)n * 128 + c * 8] = o.u;
}

// ---------------- MFMA GEMM layer 1: persistent grid-stride (best-measured, r12/r13/r15) --------
// [x|pos_n] (K=67, padded) @ W1 -> y1 fp16 [N,128]. 128x128 tiles. STRIDED tile schedule.
// B-fragments direct from global w1t (L2-resident). Separate A/O LDS regions, 2 barriers/tile.

__global__ __launch_bounds__(256, 2) void gemm1_kernel(
    const float* __restrict__ x, const float* __restrict__ pos, const int* __restrict__ idx,
    const float* __restrict__ center, const float* __restrict__ invr,
    const unsigned short* __restrict__ w1t, const float* __restrict__ b1,
    unsigned short* __restrict__ y1, float* __restrict__ gsum, float* __restrict__ gsq,
    int M, int ntiles) {
  __shared__ __align__(16) unsigned short Asm[128 * 128];
  __shared__ __align__(16) unsigned short Osm[128 * 128];
  const int tid = threadIdx.x;
  const int och = tid & 15;
  const int rr = tid >> 4;
  const int lane = tid & 63;
  const int wv = tid >> 6;
  const int wr = wv >> 1, wc = wv & 1;
  const int lr = lane & 15, lg = lane >> 4;
  const int tstep = gridDim.x;

  // persistent B fragments directly from global (K=96 -> 3 ks)
  half8 b[4][3];
#pragma unroll
  for (int cf = 0; cf < 4; ++cf) {
    int n = wc * 64 + cf * 16 + lr;
#pragma unroll
    for (int ks = 0; ks < 3; ++ks) {
      int c = ks * 4 + lg;
      b[cf][ks] = *(const half8*)&w1t[n * 128 + c * 8];
    }
  }
  float bb[4];
#pragma unroll
  for (int cf = 0; cf < 4; ++cf) bb[cf] = b1[wc * 64 + cf * 16 + lr];

  // zero A-chunks 9..11 once (staging writes only chunks 0..8; epilogue goes to Osm)
  if (tid < 128) {
    uint4 z = make_uint4(0u, 0u, 0u, 0u);
    int r = tid;
    *(uint4*)&Asm[r * 128 + ((9 ^ (r & 7)) << 3)] = z;
    *(uint4*)&Asm[r * 128 + ((10 ^ (r & 7)) << 3)] = z;
    *(uint4*)&Asm[r * 128 + ((11 ^ (r & 7)) << 3)] = z;
  }

  float4 pfx[8];
  float pp0 = 0.f, pp1 = 0.f, pp2 = 0.f, pc0 = 0.f, pc1 = 0.f, pc2 = 0.f, pir = 0.f;

  auto prefetch = [&](int tt) {
#pragma unroll
    for (int j = 0; j < 4; ++j) {
      int c = tid + 256 * j;
      int r = c >> 3, cc = c & 7;
      int row = tt * 128 + r;
      pfx[2 * j] = make_float4(0.f, 0.f, 0.f, 0.f);
      pfx[2 * j + 1] = make_float4(0.f, 0.f, 0.f, 0.f);
      if (row < M) {
        pfx[2 * j]     = *(const float4*)&x[(size_t)row * 64 + cc * 8];
        pfx[2 * j + 1] = *(const float4*)&x[(size_t)row * 64 + cc * 8 + 4];
      }
    }
    if (tid < 128) {
      int row = tt * 128 + tid;
      pp0 = pp1 = pp2 = pc0 = pc1 = pc2 = 0.f; pir = 0.f;
      if (row < M) {
        int s = idx[row];
        pp0 = pos[3 * row + 0]; pp1 = pos[3 * row + 1]; pp2 = pos[3 * row + 2];
        pc0 = center[3 * s + 0]; pc1 = center[3 * s + 1]; pc2 = center[3 * s + 2];
        pir = invr[s];
      }
    }
  };
  auto stageA = [&]() {
#pragma unroll
    for (int j = 0; j < 4; ++j) {
      int c = tid + 256 * j;
      int r = c >> 3, cc = c & 7;
      uint4 o;
      o.x = pkrtz(pfx[2 * j].x, pfx[2 * j].y);
      o.y = pkrtz(pfx[2 * j].z, pfx[2 * j].w);
      o.z = pkrtz(pfx[2 * j + 1].x, pfx[2 * j + 1].y);
      o.w = pkrtz(pfx[2 * j + 1].z, pfx[2 * j + 1].w);
      *(uint4*)&Asm[r * 128 + ((cc ^ (r & 7)) << 3)] = o;
    }
    if (tid < 128) {
      int r = tid;
      uint4 o = make_uint4(0u, 0u, 0u, 0u);
      o.x = pkrtz((pp0 - pc0) * pir, (pp1 - pc1) * pir);
      o.y = pkrtz((pp2 - pc2) * pir, 0.f);
      *(uint4*)&Asm[r * 128 + ((8 ^ (r & 7)) << 3)] = o;
    }
  };

  int t = blockIdx.x;
  prefetch(t);
  stageA();
  __syncthreads();

  float psum[8], psq[8];
#pragma unroll
  for (int c = 0; c < 8; ++c) { psum[c] = 0.f; psq[c] = 0.f; }

  const f32x4 fzero = {0.f, 0.f, 0.f, 0.f};

  for (;;) {
    const int tn = t + tstep;
    const bool more = tn < ntiles;
    if (more) prefetch(tn);  // issue early; latency hides under MFMA+epilogue
    f32x4 acc[4][4];
#pragma unroll
    for (int rf = 0; rf < 4; ++rf)
#pragma unroll
      for (int cf = 0; cf < 4; ++cf) acc[rf][cf] = fzero;
#pragma unroll
    for (int ks = 0; ks < 3; ++ks) {
      half8 a[4];
      int c = ks * 4 + lg;
#pragma unroll
      for (int rf = 0; rf < 4; ++rf) {
        int row = wr * 64 + rf * 16 + lr;
        a[rf] = *(const half8*)&Asm[row * 128 + ((c ^ (row & 7)) << 3)];
      }
#pragma unroll
      for (int cf = 0; cf < 4; ++cf)
#pragma unroll
        for (int rf = 0; rf < 4; ++rf)
          acc[rf][cf] = __builtin_amdgcn_mfma_f32_16x16x32_f16(a[rf], b[cf][ks], acc[rf][cf], 0, 0, 0);
    }
    // epilogue -> O region (Asm untouched; prev store of Osm done pre-barrier)
#pragma unroll
    for (int cf = 0; cf < 4; ++cf) {
      int col = wc * 64 + cf * 16 + lr;
#pragma unroll
      for (int rf = 0; rf < 4; ++rf) {
#pragma unroll
        for (int r = 0; r < 4; ++r) {
          int row = wr * 64 + rf * 16 + lg * 4 + r;
          Osm[row * 128 + (((col >> 3) ^ (row & 7)) << 3) + (col & 7)] = f2h(acc[rf][cf][r] + bb[cf]);
        }
      }
    }
    __syncthreads();  // O(t) complete; A(t) fully consumed
    // store O(t) + stats ; stage A(t+1) in the same phase
    const int row0 = t * 128;
#pragma unroll
    for (int j = 0; j < 8; ++j) {
      int r = rr + 16 * j;
      int row = row0 + r;
      if (row < M) {
        uint4 v = *(const uint4*)&Osm[r * 128 + ((och ^ (r & 7)) << 3)];
        *(uint4*)&y1[(size_t)row * 128 + och * 8] = v;
        union { uint4 u; _Float16 h[8]; } w; w.u = v;
#pragma unroll
        for (int c = 0; c < 8; ++c) { float f = (float)w.h[c]; psum[c] += f; psq[c] += f * f; }
      }
    }
    if (!more) break;
    stageA();
    t = tn;
    __syncthreads();  // A(t+1) ready; O free for next epilogue
  }

  __syncthreads();
  float* redS = (float*)Osm;
  float* redQ = redS + 16 * 128;
#pragma unroll
  for (int c = 0; c < 8; ++c) {
    redS[rr * 128 + och * 8 + c] = psum[c];
    redQ[rr * 128 + och * 8 + c] = psq[c];
  }
  __syncthreads();
  if (tid < 128) {
    float s = 0.f, q = 0.f;
#pragma unroll
    for (int g = 0; g < 16; ++g) { s += redS[g * 128 + tid]; q += redQ[g * 128 + tid]; }
    atomicAdd(&gsum[tid], s);
    atomicAdd(&gsq[tid], q);
  }
}

// ---------------- MFMA GEMM layer 2 + IN-REGISTER fused segment pool (best-measured, r13/r15) --
// leaky(a1*y1+c1) [1M,128] @ W2; pool max/min and column stats computed DIRECTLY from the
// f32 accumulators. Row-permuted A-staging (swap rf<->lg bit fields, an involution) makes
// each lane's 16 fragment rows CONTIGUOUS in point order -> run-detection over in-register
// sids. Double-buffered A tile -> single barrier per tile. No output LDS round-trip.
// STRIDED schedule (r16: chunked serializes atomics); UNIFORM run-scan (r17: branchy
// fast-path diverges and executes both paths).

__global__ __launch_bounds__(256, 2) void gemm2_kernel(
    const unsigned short* __restrict__ y1,
    const unsigned short* __restrict__ a1h, const unsigned short* __restrict__ c1h,
    const unsigned short* __restrict__ w2t, const float* __restrict__ b2,
    const int* __restrict__ idx,
    unsigned int* __restrict__ segmx, unsigned int* __restrict__ segmn,
    float* __restrict__ gsum, float* __restrict__ gsq,
    int M, int ntiles) {
  __shared__ __align__(16) unsigned short Abuf[2][128 * 128];
  __shared__ int sbuf[2][128];
  const int tid = threadIdx.x;
  const int col0 = blockIdx.x * 128;
  const int och = tid & 15;
  const int rr = tid >> 4;  // 0..15
  const int tstep = gridDim.y;

  // activation params for this thread's fixed k-chunk
  const _Float16* ap = (const _Float16*)a1h;
  const _Float16* cp = (const _Float16*)c1h;
  _Float16 av[8], cv[8];
#pragma unroll
  for (int q = 0; q < 8; ++q) { av[q] = ap[och * 8 + q]; cv[q] = cp[och * 8 + q]; }

  int t = blockIdx.y;
  // issue A(t0) loads + sids(t0) first (latency hides under B setup)
  uint4 pf[8];
  // row permutation: tile row p holds original row perm(p); perm swaps bits[5:4]<->[3:2]
  auto perm = [](int p) { return (p & 0x43) | ((p & 0x30) >> 2) | ((p & 0x0c) << 2); };
#pragma unroll
  for (int j = 0; j < 8; ++j) {
    int r = rr + 16 * j;
    int row = t * 128 + perm(r);
    pf[j] = make_uint4(0u, 0u, 0u, 0u);
    if (row < M) pf[j] = *(const uint4*)&y1[(size_t)row * 128 + och * 8];
  }
  if (tid < 128) {
    int row = t * 128 + tid;
    sbuf[0][tid] = (row < M) ? idx[row] : -1;
  }

  // stage B tile through Abuf[0] (once)
#pragma unroll
  for (int j = 0; j < 8; ++j) {
    int n = rr + 16 * j;
    uint4 v = *(const uint4*)&w2t[(size_t)(col0 + n) * 128 + och * 8];
    *(uint4*)&Abuf[0][n * 128 + ((och ^ (n & 7)) << 3)] = v;
  }
  __syncthreads();

  const int lane = tid & 63;
  const int wv = tid >> 6;
  const int wr = wv >> 1, wc = wv & 1;
  const int lr = lane & 15, lg = lane >> 4;

  // persistent B fragments (16 half8 = 64 VGPR)
  half8 b[4][4];
#pragma unroll
  for (int cf = 0; cf < 4; ++cf) {
    int n = wc * 64 + cf * 16 + lr;
#pragma unroll
    for (int ks = 0; ks < 4; ++ks) {
      int c = ks * 4 + lg;
      b[cf][ks] = *(const half8*)&Abuf[0][n * 128 + ((c ^ (n & 7)) << 3)];
    }
  }
  float bb[4];
#pragma unroll
  for (int cf = 0; cf < 4; ++cf) bb[cf] = b2[col0 + wc * 64 + cf * 16 + lr];
  __syncthreads();  // B-frag extraction done; Abuf[0] free

  // stage A(t0) (fused act) into Abuf[0]
#pragma unroll
  for (int j = 0; j < 8; ++j) {
    int r = rr + 16 * j;
    union { uint4 u; _Float16 h[8]; } w; w.u = pf[j];
#pragma unroll
    for (int q = 0; q < 8; ++q) {
      _Float16 v = w.h[q] * av[q] + cv[q];
      w.h[q] = (v < (_Float16)0.f) ? v * (_Float16)0.01f : v;
    }
    *(uint4*)&Abuf[0][r * 128 + ((och ^ (r & 7)) << 3)] = w.u;
  }
  __syncthreads();  // A(t0) ready

  float csum[4], csq[4];
#pragma unroll
  for (int cf = 0; cf < 4; ++cf) { csum[cf] = 0.f; csq[cf] = 0.f; }

  const f32x4 fzero = {0.f, 0.f, 0.f, 0.f};
  int p = 0;

  for (;;) {
    const int tn = t + tstep;
    const bool more = tn < ntiles;
    // issue next tile's loads + sids early (into the spare buffers)
    if (more) {
#pragma unroll
      for (int j = 0; j < 8; ++j) {
        int r = rr + 16 * j;
        int row = tn * 128 + perm(r);
        pf[j] = make_uint4(0u, 0u, 0u, 0u);
        if (row < M) pf[j] = *(const uint4*)&y1[(size_t)row * 128 + och * 8];
      }
      if (tid < 128) {
        int row = tn * 128 + tid;
        sbuf[p ^ 1][tid] = (row < M) ? idx[row] : -1;
      }
    }
    // MFMA on Abuf[p] (= permuted A(t))
    f32x4 acc[4][4];
#pragma unroll
    for (int rf = 0; rf < 4; ++rf)
#pragma unroll
      for (int cf = 0; cf < 4; ++cf) acc[rf][cf] = fzero;
    const unsigned short* Ac = Abuf[p];
#pragma unroll
    for (int ks = 0; ks < 4; ++ks) {
      half8 a[4];
      int c = ks * 4 + lg;
#pragma unroll
      for (int rf = 0; rf < 4; ++rf) {
        int row = wr * 64 + rf * 16 + lr;
        a[rf] = *(const half8*)&Ac[row * 128 + ((c ^ (row & 7)) << 3)];
      }
#pragma unroll
      for (int cf = 0; cf < 4; ++cf)
#pragma unroll
        for (int rf = 0; rf < 4; ++rf)
          acc[rf][cf] = __builtin_amdgcn_mfma_f32_16x16x32_f16(a[rf], b[cf][ks], acc[rf][cf], 0, 0, 0);
    }
    // in-register scan: lane's fragment rows are original rows wr*64+lg*16+k (k=0..15),
    // contiguous thanks to the staging permutation. acc[rf][cf][r] = row k=rf*4+r.
    {
      const int* sp = &sbuf[p][wr * 64 + lg * 16];
      int4 s0 = *(const int4*)&sp[0];
      int4 s1 = *(const int4*)&sp[4];
      int4 s2 = *(const int4*)&sp[8];
      int4 s3 = *(const int4*)&sp[12];
      int sid[16] = { s0.x, s0.y, s0.z, s0.w, s1.x, s1.y, s1.z, s1.w,
                      s2.x, s2.y, s2.z, s2.w, s3.x, s3.y, s3.z, s3.w };
#pragma unroll
      for (int cf = 0; cf < 4; ++cf) {
        const unsigned col = col0 + wc * 64 + cf * 16 + lr;
        float vv[16];
#pragma unroll
        for (int rf = 0; rf < 4; ++rf)
#pragma unroll
          for (int r = 0; r < 4; ++r) vv[rf * 4 + r] = acc[rf][cf][r] + bb[cf];
        // column stats (invalid rows have sid==-1 -> masked)
#pragma unroll
        for (int k = 0; k < 16; ++k) {
          float vk = (sid[k] >= 0) ? vv[k] : 0.f;
          csum[cf] += vk; csq[cf] += vk * vk;
        }
        // run scan + atomic flush
        int cur = sid[0];
        float mx = vv[0], mn = vv[0];
#pragma unroll
        for (int k = 1; k < 16; ++k) {
          if (sid[k] != cur) {
            if (cur >= 0) {
              atomicMax(&segmx[(size_t)cur * 256 + col], fkey(mx));
              atomicMin(&segmn[(size_t)cur * 256 + col], fkey(mn));
            }
            cur = sid[k]; mx = vv[k]; mn = vv[k];
          } else {
            mx = fmaxf(mx, vv[k]); mn = fminf(mn, vv[k]);
          }
        }
        if (cur >= 0) {
          atomicMax(&segmx[(size_t)cur * 256 + col], fkey(mx));
          atomicMin(&segmn[(size_t)cur * 256 + col], fkey(mn));
        }
      }
    }
    if (!more) break;
    // stage A(t+1) into the spare buffer (everyone finished MFMA on it pre-prev-barrier)
#pragma unroll
    for (int j = 0; j < 8; ++j) {
      int r = rr + 16 * j;
      union { uint4 u; _Float16 h[8]; } w; w.u = pf[j];
#pragma unroll
      for (int q = 0; q < 8; ++q) {
        _Float16 v = w.h[q] * av[q] + cv[q];
        w.h[q] = (v < (_Float16)0.f) ? v * (_Float16)0.01f : v;
      }
      *(uint4*)&Abuf[p ^ 1][r * 128 + ((och ^ (r & 7)) << 3)] = w.u;
    }
    t = tn; p ^= 1;
    __syncthreads();  // A(t) ready; old buffer & sbuf slot free for next prefetch
  }

  // stats: reduce across lg lanes (same column), then atomics from lg==0 lanes
#pragma unroll
  for (int cf = 0; cf < 4; ++cf) {
    csum[cf] += __shfl_xor(csum[cf], 16);
    csum[cf] += __shfl_xor(csum[cf], 32);
    csq[cf] += __shfl_xor(csq[cf], 16);
    csq[cf] += __shfl_xor(csq[cf], 32);
  }
  if (lg == 0) {
#pragma unroll
    for (int cf = 0; cf < 4; ++cf) {
      int col = col0 + wc * 64 + cf * 16 + lr;
      atomicAdd(&gsum[col], csum[cf]);
      atomicAdd(&gsq[col], csq[cf]);
    }
  }
}

// ---------------- shared fp32 GEMM micro-kernel (global MLP only; latency-dominated,
// measured faster than the 128-tile MFMA port at M=10000 -- r9 post-mortem) ----------------

__device__ __forceinline__ void mm_tile(const float* __restrict__ As, const float* __restrict__ Bs,
                                        int bk, int tr, int tc, float acc[4][8]) {
  for (int k4 = 0; k4 < bk; k4 += 4) {
    float4 a[4];
#pragma unroll
    for (int r = 0; r < 4; ++r) a[r] = *(const float4*)&As[(tr * 4 + r) * 68 + k4];
#pragma unroll
    for (int kk = 0; kk < 4; ++kk) {
      float4 w0 = *(const float4*)&Bs[(k4 + kk) * 128 + tc * 8];
      float4 w1 = *(const float4*)&Bs[(k4 + kk) * 128 + tc * 8 + 4];
#pragma unroll
      for (int r = 0; r < 4; ++r) {
        float av = (kk == 0) ? a[r].x : (kk == 1) ? a[r].y : (kk == 2) ? a[r].z : a[r].w;
        acc[r][0] = fmaf(av, w0.x, acc[r][0]);
        acc[r][1] = fmaf(av, w0.y, acc[r][1]);
        acc[r][2] = fmaf(av, w0.z, acc[r][2]);
        acc[r][3] = fmaf(av, w0.w, acc[r][3]);
        acc[r][4] = fmaf(av, w1.x, acc[r][4]);
        acc[r][5] = fmaf(av, w1.y, acc[r][5]);
        acc[r][6] = fmaf(av, w1.z, acc[r][6]);
        acc[r][7] = fmaf(av, w1.w, acc[r][7]);
      }
    }
  }
}

__device__ __forceinline__ void stats_reduce(float* redS, float* redQ,
                                             const float psum[8], const float psq[8],
                                             int tr, int tc, int tid,
                                             float* __restrict__ gsum, float* __restrict__ gsq, int col0) {
  __syncthreads();
#pragma unroll
  for (int c = 0; c < 8; ++c) {
    redS[tr * 128 + tc * 8 + c] = psum[c];
    redQ[tr * 128 + tc * 8 + c] = psq[c];
  }
  __syncthreads();
  if (tid < 128) {
    float s = 0.f, q = 0.f;
#pragma unroll
    for (int r = 0; r < 16; ++r) { s += redS[r * 128 + tid]; q += redQ[r * 128 + tid]; }
    atomicAdd(&gsum[col0 + tid], s);
    atomicAdd(&gsq[col0 + tid], q);
  }
}

// ---------------- global MLP GEMMs (M=10000) ----------------

template <bool NORM>
__global__ __launch_bounds__(256) void gemmG_kernel(
    const float* __restrict__ A, int lda, int K, int M,
    const float* __restrict__ an, const float* __restrict__ cn,
    const float* __restrict__ W, const float* __restrict__ bias,
    float* __restrict__ Y, float* __restrict__ gsum, float* __restrict__ gsq) {
  __shared__ float As[64 * 68];
  __shared__ float Bs[64 * 128];
  const int tid = threadIdx.x;
  const int row0 = blockIdx.x * 64;
  const int col0 = blockIdx.y * 128;
  const int tr = tid >> 4, tc = tid & 15;
  float acc[4][8];
#pragma unroll
  for (int r = 0; r < 4; ++r)
#pragma unroll
    for (int c = 0; c < 8; ++c) acc[r][c] = 0.f;

  const int nkb = (K + 63) >> 6;
  for (int kb = 0; kb < nkb; ++kb) {
    if (kb) __syncthreads();
    for (int e = tid; e < 64 * 64; e += 256) {
      int r = e >> 6, c = e & 63;
      int row = row0 + r, k = kb * 64 + c;
      float v = 0.f;
      if (row < M && k < K) {
        v = A[(size_t)row * lda + k];
        if (NORM) { v = an[k] * v + cn[k]; v = LEAKY(v); }
      }
      As[r * 68 + c] = v;
    }
    for (int e = tid; e < 64 * 32; e += 256) {
      int r = e >> 5, c4 = e & 31;
      int k = kb * 64 + r;
      float4 v = make_float4(0.f, 0.f, 0.f, 0.f);
      if (k < K) v = *(const float4*)&W[(size_t)k * 512 + col0 + c4 * 4];
      *(float4*)&Bs[r * 128 + c4 * 4] = v;
    }
    __syncthreads();
    mm_tile(As, Bs, 64, tr, tc, acc);
  }

  float psum[8], psq[8];
#pragma unroll
  for (int c = 0; c < 8; ++c) { psum[c] = 0.f; psq[c] = 0.f; }
#pragma unroll
  for (int r = 0; r < 4; ++r) {
    int row = row0 + tr * 4 + r;
    if (row < M) {
      float yv[8];
#pragma unroll
      for (int c = 0; c < 8; ++c) {
        yv[c] = acc[r][c] + bias[col0 + tc * 8 + c];
        psum[c] += yv[c]; psq[c] += yv[c] * yv[c];
      }
      *(float4*)&Y[(size_t)row * 512 + col0 + tc * 8] = make_float4(yv[0], yv[1], yv[2], yv[3]);
      *(float4*)&Y[(size_t)row * 512 + col0 + tc * 8 + 4] = make_float4(yv[4], yv[5], yv[6], yv[7]);
    }
  }
  stats_reduce(As, Bs, psum, psq, tr, tc, tid, gsum, gsq, col0);
}

// ---------------- finalize batch-norm affine ----------------

__global__ void finalize_kernel(const float* __restrict__ gsum, const float* __restrict__ gsq,
                                const float* __restrict__ g, const float* __restrict__ be,
                                float invn, int C, float* __restrict__ a, float* __restrict__ c,
                                unsigned short* __restrict__ ah, unsigned short* __restrict__ chh) {
  int j = blockIdx.x * blockDim.x + threadIdx.x;
  if (j >= C) return;
  float mu = gsum[j] * invn;
  float var = gsq[j] * invn - mu * mu;
  float aj = g[j] * rsqrtf(var + 1e-5f);
  float cj = be[j] - mu * aj;
  a[j] = aj;
  c[j] = cj;
  if (ah) { ah[j] = f2h(aj); chh[j] = f2h(cj); }
}

// ---------------- pool finalize: decode seg max/min, apply norm+leaky (verified r4/r11) --------
// pool val = leaky(a2*(a2>=0 ? segmax : segmin) + c2)  (affine+leaky monotone/antitone trick)

__global__ void poolfin_kernel(const unsigned int* __restrict__ segmx, const unsigned int* __restrict__ segmn,
                               const int* __restrict__ seg_start,
                               const float* __restrict__ a2, const float* __restrict__ c2,
                               const float* __restrict__ diam, float* __restrict__ hg) {
  int s = blockIdx.x;
  int j = threadIdx.x;  // 256
  bool nonempty = seg_start[s + 1] > seg_start[s];
  float aj = a2[j], cj = c2[j];
  unsigned int k = (aj >= 0.f) ? segmx[(size_t)s * 256 + j] : segmn[(size_t)s * 256 + j];
  float f = fdec(k);
  float v = aj * f + cj;
  v = LEAKY(v);
  hg[(size_t)s * 257 + j] = nonempty ? v : 0.0f;
  if (j == 0) hg[(size_t)s * 257 + 256] = diam[s];
}

// ---------------- final elementwise norm+leaky -> out ----------------

__global__ void final_kernel(const float* __restrict__ y4, const float* __restrict__ a4,
                             const float* __restrict__ c4, float* __restrict__ out, int total) {
  int i = blockIdx.x * blockDim.x + threadIdx.x;
  if (i >= total) return;
  int j = i & 511;
  float v = a4[j] * y4[i] + c4[j];
  out[i] = LEAKY(v);
}

// ---------------- launch ----------------

extern "C" void kernel_launch(void* const* d_in, const int* in_sizes, int n_in,
                              void* d_out, int out_size, void* d_ws, size_t ws_size,
                              hipStream_t stream) {
  const float* pos  = (const float*)d_in[0];
  const float* x    = (const float*)d_in[1];
  const int*   idx  = (const int*)d_in[2];
  const float* W1   = (const float*)d_in[4];
  const float* b1   = (const float*)d_in[5];
  const float* g1   = (const float*)d_in[6];
  const float* be1  = (const float*)d_in[7];
  const float* W2   = (const float*)d_in[8];
  const float* b2   = (const float*)d_in[9];
  const float* g2   = (const float*)d_in[10];
  const float* be2  = (const float*)d_in[11];
  const float* GW1  = (const float*)d_in[12];
  const float* Gb1  = (const float*)d_in[13];
  const float* Gg1  = (const float*)d_in[14];
  const float* Gbe1 = (const float*)d_in[15];
  const float* GW2  = (const float*)d_in[16];
  const float* Gb2  = (const float*)d_in[17];
  const float* Gg2  = (const float*)d_in[18];
  const float* Gbe2 = (const float*)d_in[19];
  float* out = (float*)d_out;

  const int N = in_sizes[0] / 3;  // 1,000,000
  const int S = 10000;            // num_segments (fixed by problem setup)

  char* ws = (char*)d_ws;
  size_t off = 0;
  auto take = [&](size_t bytes) -> char* {
    char* p = ws + off;
    off = (off + bytes + 255) & ~(size_t)255;
    return p;
  };
  int*   seg_start = (int*)take((size_t)(S + 1) * sizeof(int));
  float* center    = (float*)take((size_t)S * 3 * sizeof(float));
  float* invr      = (float*)take((size_t)S * sizeof(float));
  float* diam      = (float*)take((size_t)S * sizeof(float));
  float* stats     = (float*)take(2816 * sizeof(float));
  float* gsum1 = stats,        *gsq1 = stats + 128;
  float* gsum2 = stats + 256,  *gsq2 = stats + 512;
  float* gsum3 = stats + 768,  *gsq3 = stats + 1280;
  float* gsum4 = stats + 1792, *gsq4 = stats + 2304;
  float* par = (float*)take(2816 * sizeof(float));
  float* a1 = par,        *c1 = par + 256;
  float* a2 = par + 512,  *c2 = par + 768;
  float* a3 = par + 1024, *c3 = par + 1536;
  float* a4 = par + 2048, *c4 = par + 2560;
  unsigned short* a1h = (unsigned short*)take(128 * 2);
  unsigned short* c1h = (unsigned short*)take(128 * 2);
  unsigned short* w1t = (unsigned short*)take((size_t)128 * 128 * 2);
  unsigned short* w2t = (unsigned short*)take((size_t)256 * 128 * 2);
  float* hg = (float*)take((size_t)S * 257 * sizeof(float));
  float* y3 = (float*)take((size_t)S * 512 * sizeof(float));
  float* y4 = (float*)take((size_t)S * 512 * sizeof(float));
  unsigned int* segmx = (unsigned int*)take((size_t)S * 256 * sizeof(unsigned int));
  unsigned int* segmn = (unsigned int*)take((size_t)S * 256 * sizeof(unsigned int));
  unsigned short* y1 = (unsigned short*)take((size_t)N * 128 * 2);
  (void)ws_size; (void)n_in; (void)out_size;

  hipMemsetAsync(stats, 0, 2816 * sizeof(float), stream);
  hipMemsetAsync(segmx, 0x00, (size_t)S * 256 * sizeof(unsigned int), stream);
  hipMemsetAsync(segmn, 0xFF, (size_t)S * 256 * sizeof(unsigned int), stream);

  wconv_kernel<<<(128 * 16 + 255) / 256, 256, 0, stream>>>(W1, 67, 128, w1t);
  wconv_kernel<<<(256 * 16 + 255) / 256, 256, 0, stream>>>(W2, 128, 256, w2t);

  seg_lb_kernel<<<(S + 1 + 255) / 256, 256, 0, stream>>>(idx, N, S, seg_start);
  seg_stat_kernel<<<S, 64, 0, stream>>>(pos, seg_start, center, invr, diam);

  const int ntiles = (N + 127) / 128;
  gemm1_kernel<<<512, 256, 0, stream>>>(x, pos, idx, center, invr, w1t, b1, y1, gsum1, gsq1, N, ntiles);
  finalize_kernel<<<1, 128, 0, stream>>>(gsum1, gsq1, g1, be1, 1.0f / (float)N, 128, a1, c1, a1h, c1h);

  gemm2_kernel<<<dim3(2, 256), 256, 0, stream>>>(y1, a1h, c1h, w2t, b2, idx, segmx, segmn,
                                                 gsum2, gsq2, N, ntiles);
  finalize_kernel<<<1, 256, 0, stream>>>(gsum2, gsq2, g2, be2, 1.0f / (float)N, 256, a2, c2, nullptr, nullptr);

  poolfin_kernel<<<S, 256, 0, stream>>>(segmx, segmn, seg_start, a2, c2, diam, hg);

  gemmG_kernel<false><<<dim3((S + 63) / 64, 4), 256, 0, stream>>>(hg, 257, 257, S, nullptr, nullptr,
                                                                  GW1, Gb1, y3, gsum3, gsq3);
  finalize_kernel<<<2, 256, 0, stream>>>(gsum3, gsq3, Gg1, Gbe1, 1.0f / (float)S, 512, a3, c3, nullptr, nullptr);

  gemmG_kernel<true><<<dim3((S + 63) / 64, 4), 256, 0, stream>>>(y3, 512, 512, S, a3, c3,
                                                                 GW2, Gb2, y4, gsum4, gsq4);
  finalize_kernel<<<2, 256, 0, stream>>>(gsum4, gsq4, Gg2, Gbe2, 1.0f / (float)S, 512, a4, c4, nullptr, nullptr);

  final_kernel<<<(S * 512 + 255) / 256, 256, 0, stream>>>(y4, a4, c4, out, S * 512);
}